// Round 6
// baseline (1308.743 us; speedup 1.0000x reference)
//
#include <hip/hip_runtime.h>
#include <math.h>

#define NN 100000
#define DD 128
#define CC 64
#define TT 8
#define NS 50000

typedef __attribute__((ext_vector_type(4))) float f32x4;
typedef __attribute__((ext_vector_type(8))) short bf16x8;

__device__ __forceinline__ short f2bf(float f) {
    union { float f; unsigned u; } v; v.f = f;
    unsigned r = v.u + 0x7fffu + ((v.u >> 16) & 1u);
    return (short)(r >> 16);
}
// tanh-form GELU via hardware exp: max |diff| vs exact erf-GELU ~3e-3
__device__ __forceinline__ float gelu(float x) {
    float t = x + 0.044715f * x * x * x;
    return x / (1.0f + __expf(-1.5957691216f * t));
}

// ---------------- weight -> MFMA-fragment prearrange (bf16) ----------------
__global__ void prep_weights(const float* __restrict__ W, short* __restrict__ dst,
                             int KSTEPS, int total, int N) {
    int s = blockIdx.x * 256 + threadIdx.x;
    if (s >= total) return;
    int lane = s & 63;
    int ks = (s >> 6) % KSTEPS;
    int n = s / (64 * KSTEPS);
    int kb = ks * 32 + (lane >> 4) * 8;
    int col = n * 16 + (lane & 15);
    bf16x8 o;
    #pragma unroll
    for (int j = 0; j < 8; ++j) o[j] = f2bf(W[(size_t)(kb + j) * N + col]);
    *(bf16x8*)(dst + (size_t)s * 8) = o;
}

// ---------------- per-(node,g) contribution counts ----------------
__global__ void flag_kernel(const int* __restrict__ idx, int* __restrict__ pernode, int G) {
    int i = blockIdx.x * 256 + threadIdx.x;
    if (i >= G * NS) return;
    int g = i / NS;
    atomicAdd(&pernode[idx[i] * 8 + g], 1);
}

// ------- active lists + contributor offsets + node->pos (wave-aggregated) ---
__global__ void compact_kernel(const int* __restrict__ pernode, int* __restrict__ cursor,
                               int* __restrict__ lists, int* __restrict__ node2pos,
                               int* __restrict__ cnts, int* __restrict__ alloc) {
    int g = blockIdx.y;
    int node = blockIdx.x * 256 + threadIdx.x;
    int c = (node < NN) ? pernode[node * 8 + g] : 0;
    bool active = c > 0;
    int lane = threadIdx.x & 63;
    unsigned long long m = __ballot(active);
    int rank = __popcll(m & ((1ull << lane) - 1ull));
    int nact = __popcll(m);
    int lbase = 0;
    if (lane == 0 && nact > 0) lbase = atomicAdd(&cnts[g], nact);
    lbase = __shfl(lbase, 0);
    if (active) {
        lists[(size_t)g * NS + lbase + rank] = node;
        node2pos[node * 8 + g] = lbase + rank;
    }
    // contributor-offset via wave inclusive scan of counts
    int pre = c;
    #pragma unroll
    for (int off = 1; off <= 32; off <<= 1) {
        int t = __shfl_up(pre, off);
        if (lane >= off) pre += t;
    }
    int wtot = __shfl(pre, 63);
    int obase = 0;
    if (lane == 0 && wtot > 0) obase = atomicAdd(&alloc[g], wtot);
    obase = __shfl(obase, 0);
    if (active) cursor[node * 8 + g] = obase + (pre - c);
}

// ---------------- fill contributor positions (counting sort) ----------------
__global__ void fill_kernel(const int* __restrict__ idx, int* __restrict__ cursor,
                            int* __restrict__ positions, int G) {
    int i = blockIdx.x * 256 + threadIdx.x;
    if (i >= G * NS) return;
    int g = i / NS, s = i - g * NS;
    int node = idx[i];
    int p = atomicAdd(&cursor[node * 8 + g], 1);
    positions[(size_t)g * NS + p] = s;
}

// ---- fused mlp_d: reg-layout aggregate+LN -> G1+GELU -> G2 -> compact h ----
// 512 threads = 8 waves, 16 rows/wave, strip=128 rows.
// LDS 64KB (per-wave H only); W frags from global (L2) -> 2 blocks/CU.
__global__ __launch_bounds__(512, 4) void mlp_d_kernel(
    const float* __restrict__ x, const float* __restrict__ bd,
    const float* __restrict__ lng, const float* __restrict__ lnb,
    const short* __restrict__ pW1, const short* __restrict__ pW2,
    const float* __restrict__ bd1, const float* __restrict__ bd2,
    const int* __restrict__ lists, const int* __restrict__ cnts,
    const int* __restrict__ pernode, const int* __restrict__ cursor,
    const int* __restrict__ positions,
    float* __restrict__ h_c, int G) {
    __shared__ short sH[8][4096];   // per-wave H [16][256] bf16, 8KB each

    const int tid = threadIdx.x;
    const int wave = tid >> 6, lane = tid & 63;
    short* myb = sH[wave];
    const int arow = lane & 15;
    const int kgrp = lane >> 4;
    const int swa = (arow & 7) << 4;
    const int MAXS = (NS + 127) / 128;   // 391

    for (int w = blockIdx.x; w < G * MAXS; w += gridDim.x) {
        const int g = w % G;
        const int strip = w / G;
        const int nrows = cnts[g];
        if (strip * 128 >= nrows) continue;
        const int* list = lists + (size_t)g * NS;
        const int* pos_g = positions + (size_t)g * NS;
        const float* x_g = x + (size_t)g * NS * DD;
        float* h_cg = h_c + (size_t)g * NS * CC;
        const int row0 = strip * 128 + wave * 16;

        // ---- aggregate + LN directly in A-fragment layout
        const int gi = row0 + arow;
        const int node = list[gi < nrows ? gi : (nrows - 1)];
        const int cnt = pernode[node * 8 + g];
        const int off = cursor[node * 8 + g] - cnt;
        float v[32];
        {
            const float* bp = bd + (size_t)node * DD + kgrp * 8;
            #pragma unroll
            for (int ks = 0; ks < 4; ++ks) {
                float4 b0 = *(const float4*)(bp + ks * 32);
                float4 b1 = *(const float4*)(bp + ks * 32 + 4);
                v[ks*8+0]=b0.x; v[ks*8+1]=b0.y; v[ks*8+2]=b0.z; v[ks*8+3]=b0.w;
                v[ks*8+4]=b1.x; v[ks*8+5]=b1.y; v[ks*8+6]=b1.z; v[ks*8+7]=b1.w;
            }
        }
        for (int j = 0; j < cnt; ++j) {
            int s = pos_g[off + j];
            const float* xp = x_g + (size_t)s * DD + kgrp * 8;
            #pragma unroll
            for (int ks = 0; ks < 4; ++ks) {
                float4 a0 = *(const float4*)(xp + ks * 32);
                float4 a1 = *(const float4*)(xp + ks * 32 + 4);
                v[ks*8+0]+=a0.x; v[ks*8+1]+=a0.y; v[ks*8+2]+=a0.z; v[ks*8+3]+=a0.w;
                v[ks*8+4]+=a1.x; v[ks*8+5]+=a1.y; v[ks*8+6]+=a1.z; v[ks*8+7]+=a1.w;
            }
        }
        float s1 = 0.f;
        #pragma unroll
        for (int j = 0; j < 32; ++j) s1 += v[j];
        s1 += __shfl_xor(s1, 16); s1 += __shfl_xor(s1, 32);
        float mu = s1 * 0.0078125f;
        float s2 = 0.f;
        #pragma unroll
        for (int j = 0; j < 32; ++j) { float d = v[j] - mu; s2 += d * d; }
        s2 += __shfl_xor(s2, 16); s2 += __shfl_xor(s2, 32);
        float rs = rsqrtf(s2 * 0.0078125f + 1e-5f);
        bf16x8 afr[4];
        {
            const float* gp = lng + kgrp * 8;
            const float* bbp = lnb + kgrp * 8;
            #pragma unroll
            for (int ks = 0; ks < 4; ++ks) {
                float4 g0 = *(const float4*)(gp + ks * 32);
                float4 g1 = *(const float4*)(gp + ks * 32 + 4);
                float4 c0 = *(const float4*)(bbp + ks * 32);
                float4 c1 = *(const float4*)(bbp + ks * 32 + 4);
                afr[ks][0] = f2bf((v[ks*8+0]-mu)*rs*g0.x + c0.x);
                afr[ks][1] = f2bf((v[ks*8+1]-mu)*rs*g0.y + c0.y);
                afr[ks][2] = f2bf((v[ks*8+2]-mu)*rs*g0.z + c0.z);
                afr[ks][3] = f2bf((v[ks*8+3]-mu)*rs*g0.w + c0.w);
                afr[ks][4] = f2bf((v[ks*8+4]-mu)*rs*g1.x + c1.x);
                afr[ks][5] = f2bf((v[ks*8+5]-mu)*rs*g1.y + c1.y);
                afr[ks][6] = f2bf((v[ks*8+6]-mu)*rs*g1.z + c1.z);
                afr[ks][7] = f2bf((v[ks*8+7]-mu)*rs*g1.w + c1.w);
            }
        }
        // ---- GEMM1 (16x256, K=128) in two n-halves; B-frags from global (L2)
        #pragma unroll
        for (int half = 0; half < 2; ++half) {
            f32x4 acc[8];
            #pragma unroll
            for (int n8 = 0; n8 < 8; ++n8) acc[n8] = (f32x4){0.f, 0.f, 0.f, 0.f};
            #pragma unroll
            for (int ks = 0; ks < 4; ++ks) {
                #pragma unroll
                for (int n8 = 0; n8 < 8; ++n8) {
                    int n = half * 8 + n8;
                    bf16x8 bf = *(const bf16x8*)(pW1 + (size_t)(((n << 2) | ks) * 64 + lane) * 8);
                    acc[n8] = __builtin_amdgcn_mfma_f32_16x16x32_bf16(afr[ks], bf, acc[n8], 0, 0, 0);
                }
            }
            #pragma unroll
            for (int n8 = 0; n8 < 8; ++n8) {
                int n = half * 8 + n8;
                float bias = bd1[n * 16 + arow];
                #pragma unroll
                for (int rr = 0; rr < 4; ++rr) {
                    float vv = gelu(acc[n8][rr] + bias);
                    int hr = kgrp * 4 + rr;
                    int boff = ((n * 16 + arow) * 2) ^ ((hr & 7) << 4);
                    myb[hr * 256 + (boff >> 1)] = f2bf(vv);
                }
            }
        }
        // ---- GEMM2 (16x64, K=256); A from LDS H, B-frags from global
        f32x4 acc2[4];
        #pragma unroll
        for (int n = 0; n < 4; ++n) acc2[n] = (f32x4){0.f, 0.f, 0.f, 0.f};
        #pragma unroll
        for (int ks = 0; ks < 8; ++ks) {
            int boff = (ks * 64 + kgrp * 16) ^ swa;
            bf16x8 af = *(const bf16x8*)(myb + arow * 256 + (boff >> 1));
            #pragma unroll
            for (int n = 0; n < 4; ++n) {
                bf16x8 bf = *(const bf16x8*)(pW2 + (size_t)(((n << 3) | ks) * 64 + lane) * 8);
                acc2[n] = __builtin_amdgcn_mfma_f32_16x16x32_bf16(af, bf, acc2[n], 0, 0, 0);
            }
        }
        // ---- epilogue: compact h (coalesced by list position)
        #pragma unroll
        for (int rr = 0; rr < 4; ++rr) {
            int gi2 = row0 + kgrp * 4 + rr;
            if (gi2 < nrows) {
                #pragma unroll
                for (int n = 0; n < 4; ++n)
                    h_cg[(size_t)gi2 * CC + n * 16 + arow] = acc2[n][rr] + bd2[n * 16 + arow];
            }
        }
    }
}

// ---------------- fused mlp_u: gather(compact h)+LN -> G3+GELU -> G4 --------
// LDS 32KB (per-wave U only); W frags from global -> 2 blocks/CU.
__global__ __launch_bounds__(512, 4) void mlp_u_kernel(
    const float* __restrict__ h_c, const int* __restrict__ idx,
    const int* __restrict__ node2pos,
    const float* __restrict__ lng, const float* __restrict__ lnb,
    const short* __restrict__ pW3, const short* __restrict__ pW4,
    const float* __restrict__ bu1, const float* __restrict__ bu2,
    float* __restrict__ out, int G) {
    __shared__ short sU[8][2048];   // per-wave U [16][128] bf16, 4KB each

    const int tid = threadIdx.x;
    const int wave = tid >> 6, lane = tid & 63;
    short* myb = sU[wave];
    const int arow = lane & 15;
    const int kgrp = lane >> 4;
    const int swa = (arow & 7) << 4;
    const int MAXS = (NS + 127) / 128;   // 391

    for (int w = blockIdx.x; w < G * MAXS; w += gridDim.x) {
        const int g = w % G;
        const int strip = w / G;
        const int* idx_t = idx + (size_t)g * NS;
        const float* h_g = h_c + (size_t)g * NS * CC;
        float* out_t = out + (size_t)g * NS * DD;
        const int row0 = strip * 128 + wave * 16;

        // ---- gather + LN in A-fragment layout
        const int gi = row0 + arow;
        const int srow = gi < NS ? gi : (NS - 1);
        const int node = idx_t[srow];
        const int pos = node2pos[node * 8 + g];
        const float* hp = h_g + (size_t)pos * CC + kgrp * 8;
        float v[16];
        #pragma unroll
        for (int ks = 0; ks < 2; ++ks) {
            float4 a0 = *(const float4*)(hp + ks * 32);
            float4 a1 = *(const float4*)(hp + ks * 32 + 4);
            v[ks*8+0]=a0.x; v[ks*8+1]=a0.y; v[ks*8+2]=a0.z; v[ks*8+3]=a0.w;
            v[ks*8+4]=a1.x; v[ks*8+5]=a1.y; v[ks*8+6]=a1.z; v[ks*8+7]=a1.w;
        }
        float s1 = 0.f;
        #pragma unroll
        for (int j = 0; j < 16; ++j) s1 += v[j];
        s1 += __shfl_xor(s1, 16); s1 += __shfl_xor(s1, 32);
        float mu = s1 * 0.015625f;
        float s2 = 0.f;
        #pragma unroll
        for (int j = 0; j < 16; ++j) { float d = v[j] - mu; s2 += d * d; }
        s2 += __shfl_xor(s2, 16); s2 += __shfl_xor(s2, 32);
        float rs = rsqrtf(s2 * 0.015625f + 1e-5f);
        bf16x8 afr[2];
        {
            const float* gp = lng + kgrp * 8;
            const float* bbp = lnb + kgrp * 8;
            #pragma unroll
            for (int ks = 0; ks < 2; ++ks) {
                float4 g0 = *(const float4*)(gp + ks * 32);
                float4 g1 = *(const float4*)(gp + ks * 32 + 4);
                float4 c0 = *(const float4*)(bbp + ks * 32);
                float4 c1 = *(const float4*)(bbp + ks * 32 + 4);
                afr[ks][0] = f2bf((v[ks*8+0]-mu)*rs*g0.x + c0.x);
                afr[ks][1] = f2bf((v[ks*8+1]-mu)*rs*g0.y + c0.y);
                afr[ks][2] = f2bf((v[ks*8+2]-mu)*rs*g0.z + c0.z);
                afr[ks][3] = f2bf((v[ks*8+3]-mu)*rs*g0.w + c0.w);
                afr[ks][4] = f2bf((v[ks*8+4]-mu)*rs*g1.x + c1.x);
                afr[ks][5] = f2bf((v[ks*8+5]-mu)*rs*g1.y + c1.y);
                afr[ks][6] = f2bf((v[ks*8+6]-mu)*rs*g1.z + c1.z);
                afr[ks][7] = f2bf((v[ks*8+7]-mu)*rs*g1.w + c1.w);
            }
        }
        // ---- GEMM3 (16x128, K=64); B-frags from global
        f32x4 a3[8];
        #pragma unroll
        for (int n = 0; n < 8; ++n) a3[n] = (f32x4){0.f, 0.f, 0.f, 0.f};
        #pragma unroll
        for (int ks = 0; ks < 2; ++ks) {
            #pragma unroll
            for (int n = 0; n < 8; ++n) {
                bf16x8 bf = *(const bf16x8*)(pW3 + (size_t)(((n << 1) | ks) * 64 + lane) * 8);
                a3[n] = __builtin_amdgcn_mfma_f32_16x16x32_bf16(afr[ks], bf, a3[n], 0, 0, 0);
            }
        }
        // ---- bias + GELU -> U (LDS, swizzled)
        #pragma unroll
        for (int n = 0; n < 8; ++n) {
            float bias = bu1[n * 16 + arow];
            #pragma unroll
            for (int rr = 0; rr < 4; ++rr) {
                float vv = gelu(a3[n][rr] + bias);
                int hr = kgrp * 4 + rr;
                int boff = ((n * 16 + arow) * 2) ^ ((hr & 7) << 4);
                myb[hr * 128 + (boff >> 1)] = f2bf(vv);
            }
        }
        // ---- GEMM4 (16x128, K=128); A from LDS U, B-frags from global
        f32x4 a4[8];
        #pragma unroll
        for (int n = 0; n < 8; ++n) a4[n] = (f32x4){0.f, 0.f, 0.f, 0.f};
        #pragma unroll
        for (int ks = 0; ks < 4; ++ks) {
            int boff = (ks * 64 + kgrp * 16) ^ swa;
            bf16x8 af = *(const bf16x8*)(myb + arow * 128 + (boff >> 1));
            #pragma unroll
            for (int n = 0; n < 8; ++n) {
                bf16x8 bf = *(const bf16x8*)(pW4 + (size_t)(((n << 2) | ks) * 64 + lane) * 8);
                a4[n] = __builtin_amdgcn_mfma_f32_16x16x32_bf16(af, bf, a4[n], 0, 0, 0);
            }
        }
        // ---- epilogue
        #pragma unroll
        for (int rr = 0; rr < 4; ++rr) {
            int gi2 = row0 + kgrp * 4 + rr;
            if (gi2 < NS) {
                #pragma unroll
                for (int n = 0; n < 8; ++n)
                    out_t[(size_t)gi2 * DD + n * 16 + arow] = a4[n][rr] + bu2[n * 16 + arow];
            }
        }
    }
}

extern "C" void kernel_launch(void* const* d_in, const int* in_sizes, int n_in,
                              void* d_out, int out_size, void* d_ws, size_t ws_size,
                              hipStream_t stream) {
    const float* x       = (const float*)d_in[0];
    const int*   indices = (const int*)d_in[1];
    const float* bd      = (const float*)d_in[2];
    const float* ln_d_g  = (const float*)d_in[3];
    const float* ln_d_b  = (const float*)d_in[4];
    const float* Wd1     = (const float*)d_in[5];
    const float* bd1     = (const float*)d_in[6];
    const float* Wd2     = (const float*)d_in[7];
    const float* bd2     = (const float*)d_in[8];
    const float* ln_u_g  = (const float*)d_in[9];
    const float* ln_u_b  = (const float*)d_in[10];
    const float* Wu1     = (const float*)d_in[11];
    const float* bu1     = (const float*)d_in[12];
    const float* Wu2     = (const float*)d_in[13];
    const float* bu2     = (const float*)d_in[14];
    float* out = (float*)d_out;

    // choose largest power-of-2 group size that fits ws (h_c is the big buffer)
    int G = 8;
    while (G > 1) {
        size_t need = (size_t)G * NS * CC * 4 + (size_t)NN * 8 * 4 * 3
                    + (size_t)8 * NS * 4 * 2 + 4 * TT * 4
                    + (size_t)9216 * 16 + 48 * 256;
        if (need <= ws_size) break;
        G >>= 1;
    }

    char* ws = (char*)d_ws;
    size_t o = 0;
    auto alloc_b = [&](size_t bytes) { char* p = ws + o; o = (o + bytes + 255) & ~(size_t)255; return p; };
    float* h_c      = (float*)alloc_b((size_t)G * NS * CC * 4);
    int*   pernode  = (int*)alloc_b((size_t)NN * 8 * 4);
    int*   cursor   = (int*)alloc_b((size_t)NN * 8 * 4);
    int*   node2pos = (int*)alloc_b((size_t)NN * 8 * 4);
    int*   lists    = (int*)alloc_b((size_t)8 * NS * 4);
    int*   positions= (int*)alloc_b((size_t)8 * NS * 4);
    int*   cnts     = (int*)alloc_b(8 * 4);
    int*   allocg   = (int*)alloc_b(8 * 4);
    short* pW1      = (short*)alloc_b((size_t)4096 * 16);
    short* pW2      = (short*)alloc_b((size_t)2048 * 16);
    short* pW3      = (short*)alloc_b((size_t)1024 * 16);
    short* pW4      = (short*)alloc_b((size_t)2048 * 16);

    prep_weights<<<16, 256, 0, stream>>>(Wd1, pW1, 4, 4096, 256);
    prep_weights<<<8, 256, 0, stream>>>(Wd2, pW2, 8, 2048, 64);
    prep_weights<<<4, 256, 0, stream>>>(Wu1, pW3, 2, 1024, 128);
    prep_weights<<<8, 256, 0, stream>>>(Wu2, pW4, 4, 2048, 128);

    for (int g0 = 0; g0 < TT; g0 += G) {
        const float* x_g   = x + (size_t)g0 * NS * DD;
        const int*   idx_g = indices + (size_t)g0 * NS;
        float*       out_g = out + (size_t)g0 * NS * DD;

        hipMemsetAsync(pernode, 0, (size_t)NN * 8 * 4, stream);
        hipMemsetAsync(cnts, 0, 8 * 4, stream);
        hipMemsetAsync(allocg, 0, 8 * 4, stream);

        flag_kernel<<<(G * NS + 255) / 256, 256, 0, stream>>>(idx_g, pernode, G);
        compact_kernel<<<dim3((NN + 255) / 256, G), 256, 0, stream>>>(pernode, cursor,
                                                                      lists, node2pos,
                                                                      cnts, allocg);
        fill_kernel<<<(G * NS + 255) / 256, 256, 0, stream>>>(idx_g, cursor, positions, G);
        mlp_d_kernel<<<512, 512, 0, stream>>>(x_g, bd, ln_d_g, ln_d_b, pW1, pW2,
                                              bd1, bd2, lists, cnts, pernode, cursor,
                                              positions, h_c, G);
        mlp_u_kernel<<<512, 512, 0, stream>>>(h_c, idx_g, node2pos, ln_u_g, ln_u_b,
                                              pW3, pW4, bu1, bu2, out_g, G);
    }
}

// Round 7
// 533.463 us; speedup vs baseline: 2.4533x; 2.4533x over previous
//
#include <hip/hip_runtime.h>
#include <math.h>

#define NN 100000
#define DD 128
#define CC 64
#define TT 8
#define NS 50000
#define G8 8
#define MAXS 391   // ceil(NS/128)

typedef __attribute__((ext_vector_type(4))) float f32x4;
typedef __attribute__((ext_vector_type(8))) short bf16x8;

__device__ __forceinline__ short f2bf(float f) {
    union { float f; unsigned u; } v; v.f = f;
    unsigned r = v.u + 0x7fffu + ((v.u >> 16) & 1u);
    return (short)(r >> 16);
}
// tanh-form GELU via hardware exp: max |diff| vs exact erf-GELU ~3e-3
__device__ __forceinline__ float gelu(float x) {
    float t = x + 0.044715f * x * x * x;
    return x / (1.0f + __expf(-1.5957691216f * t));
}

// ---------------- weight -> MFMA-fragment prearrange (bf16) ----------------
__global__ void prep_weights(const float* __restrict__ W, short* __restrict__ dst,
                             int KSTEPS, int total, int N) {
    int s = blockIdx.x * 256 + threadIdx.x;
    if (s >= total) return;
    int lane = s & 63;
    int ks = (s >> 6) % KSTEPS;
    int n = s / (64 * KSTEPS);
    int kb = ks * 32 + (lane >> 4) * 8;
    int col = n * 16 + (lane & 15);
    bf16x8 o;
    #pragma unroll
    for (int j = 0; j < 8; ++j) o[j] = f2bf(W[(size_t)(kb + j) * N + col]);
    *(bf16x8*)(dst + (size_t)s * 8) = o;
}

// ---------------- per-(node,g) contribution counts ----------------
__global__ void flag_kernel(const int* __restrict__ idx, int* __restrict__ pernode) {
    int i = blockIdx.x * 256 + threadIdx.x;
    if (i >= G8 * NS) return;
    int g = i / NS;
    atomicAdd(&pernode[idx[i] * 8 + g], 1);
}

// ------- active lists + contributor offsets (wave-aggregated atomics) -------
__global__ void compact_kernel(const int* __restrict__ pernode, int* __restrict__ cursor,
                               int* __restrict__ lists, int* __restrict__ cnts,
                               int* __restrict__ alloc) {
    int g = blockIdx.y;
    int node = blockIdx.x * 256 + threadIdx.x;
    int c = (node < NN) ? pernode[node * 8 + g] : 0;
    bool active = c > 0;
    int lane = threadIdx.x & 63;
    unsigned long long m = __ballot(active);
    int rank = __popcll(m & ((1ull << lane) - 1ull));
    int nact = __popcll(m);
    int lbase = 0;
    if (lane == 0 && nact > 0) lbase = atomicAdd(&cnts[g], nact);
    lbase = __shfl(lbase, 0);
    if (active) lists[(size_t)g * NS + lbase + rank] = node;
    int pre = c;
    #pragma unroll
    for (int off = 1; off <= 32; off <<= 1) {
        int t = __shfl_up(pre, off);
        if (lane >= off) pre += t;
    }
    int wtot = __shfl(pre, 63);
    int obase = 0;
    if (lane == 0 && wtot > 0) obase = atomicAdd(&alloc[g], wtot);
    obase = __shfl(obase, 0);
    if (active) cursor[node * 8 + g] = obase + (pre - c);
}

// ---------------- fill contributor positions (counting sort) ----------------
__global__ void fill_kernel(const int* __restrict__ idx, int* __restrict__ cursor,
                            int* __restrict__ positions) {
    int i = blockIdx.x * 256 + threadIdx.x;
    if (i >= G8 * NS) return;
    int g = i / NS, s = i - g * NS;
    int node = idx[i];
    int p = atomicAdd(&cursor[node * 8 + g], 1);
    positions[(size_t)g * NS + p] = s;
}

// ---- fully fused: aggregate+LN_d -> G1+GELU -> G2 -> LN_u -> G3+GELU -> G4
//      -> broadcast out rows to all subnode positions. Per unique active node.
// 512 threads = 8 waves, 16 nodes/wave, strip = 128 nodes.
// LDS: W1 64K + W2 32K + W3 16K + W4 32K + 8x2K wave buffers = 160KB exactly.
// No barriers in the main loop (wave-private buffers) -> waves slip freely.
__global__ __launch_bounds__(512, 2) void fused_kernel(
    const float* __restrict__ x, const float* __restrict__ bd,
    const float* __restrict__ lndg, const float* __restrict__ lndb,
    const short* __restrict__ pW1, const short* __restrict__ pW2,
    const short* __restrict__ pW3, const short* __restrict__ pW4,
    const float* __restrict__ bd1, const float* __restrict__ bd2,
    const float* __restrict__ lnug, const float* __restrict__ lnub,
    const float* __restrict__ bu1, const float* __restrict__ bu2,
    const int* __restrict__ lists, const int* __restrict__ cnts,
    const int* __restrict__ pernode, const int* __restrict__ cursor,
    const int* __restrict__ positions, float* __restrict__ out) {
    __shared__ short sW1[4096 * 8];
    __shared__ short sW2[2048 * 8];
    __shared__ short sW3[1024 * 8];
    __shared__ short sW4[2048 * 8];
    __shared__ short sBuf[8][1024];   // 2KB per wave

    const int tid = threadIdx.x;
    for (int s = tid; s < 4096; s += 512)
        *(bf16x8*)(sW1 + s * 8) = *(const bf16x8*)(pW1 + (size_t)s * 8);
    for (int s = tid; s < 2048; s += 512)
        *(bf16x8*)(sW2 + s * 8) = *(const bf16x8*)(pW2 + (size_t)s * 8);
    for (int s = tid; s < 1024; s += 512)
        *(bf16x8*)(sW3 + s * 8) = *(const bf16x8*)(pW3 + (size_t)s * 8);
    for (int s = tid; s < 2048; s += 512)
        *(bf16x8*)(sW4 + s * 8) = *(const bf16x8*)(pW4 + (size_t)s * 8);
    __syncthreads();

    const int wave = tid >> 6, lane = tid & 63;
    short* myb = sBuf[wave];
    const int arow = lane & 15;
    const int kgrp = lane >> 4;

    for (int w = blockIdx.x; w < G8 * MAXS; w += gridDim.x) {
        const int g = w % G8;
        const int strip = w / G8;
        const int nrows = cnts[g];
        if (strip * 128 >= nrows) continue;
        const int* list = lists + (size_t)g * NS;
        const int* pos_g = positions + (size_t)g * NS;
        const float* x_g = x + (size_t)g * NS * DD;
        float* out_g = out + (size_t)g * NS * DD;
        const int row0 = strip * 128 + wave * 16;

        // ---- aggregate contributors + bd, LN_d, directly in A-frag layout
        const int gi = row0 + arow;
        const int node = list[gi < nrows ? gi : nrows - 1];
        const int cnt = pernode[node * 8 + g];
        const int off = cursor[node * 8 + g] - cnt;
        float v[32];
        {
            const float* bp = bd + (size_t)node * DD + kgrp * 8;
            #pragma unroll
            for (int ks = 0; ks < 4; ++ks) {
                float4 b0 = *(const float4*)(bp + ks * 32);
                float4 b1 = *(const float4*)(bp + ks * 32 + 4);
                v[ks*8+0]=b0.x; v[ks*8+1]=b0.y; v[ks*8+2]=b0.z; v[ks*8+3]=b0.w;
                v[ks*8+4]=b1.x; v[ks*8+5]=b1.y; v[ks*8+6]=b1.z; v[ks*8+7]=b1.w;
            }
        }
        for (int j = 0; j < cnt; ++j) {
            int s = pos_g[off + j];
            const float* xp = x_g + (size_t)s * DD + kgrp * 8;
            #pragma unroll
            for (int ks = 0; ks < 4; ++ks) {
                float4 a0 = *(const float4*)(xp + ks * 32);
                float4 a1 = *(const float4*)(xp + ks * 32 + 4);
                v[ks*8+0]+=a0.x; v[ks*8+1]+=a0.y; v[ks*8+2]+=a0.z; v[ks*8+3]+=a0.w;
                v[ks*8+4]+=a1.x; v[ks*8+5]+=a1.y; v[ks*8+6]+=a1.z; v[ks*8+7]+=a1.w;
            }
        }
        float s1 = 0.f;
        #pragma unroll
        for (int j = 0; j < 32; ++j) s1 += v[j];
        s1 += __shfl_xor(s1, 16); s1 += __shfl_xor(s1, 32);
        float mu = s1 * 0.0078125f;
        float s2 = 0.f;
        #pragma unroll
        for (int j = 0; j < 32; ++j) { float d = v[j] - mu; s2 += d * d; }
        s2 += __shfl_xor(s2, 16); s2 += __shfl_xor(s2, 32);
        float rs = rsqrtf(s2 * 0.0078125f + 1e-5f);
        bf16x8 afr[4];
        {
            const float* gp = lndg + kgrp * 8;
            const float* bbp = lndb + kgrp * 8;
            #pragma unroll
            for (int ks = 0; ks < 4; ++ks) {
                float4 g0 = *(const float4*)(gp + ks * 32);
                float4 g1 = *(const float4*)(gp + ks * 32 + 4);
                float4 c0 = *(const float4*)(bbp + ks * 32);
                float4 c1 = *(const float4*)(bbp + ks * 32 + 4);
                afr[ks][0] = f2bf((v[ks*8+0]-mu)*rs*g0.x + c0.x);
                afr[ks][1] = f2bf((v[ks*8+1]-mu)*rs*g0.y + c0.y);
                afr[ks][2] = f2bf((v[ks*8+2]-mu)*rs*g0.z + c0.z);
                afr[ks][3] = f2bf((v[ks*8+3]-mu)*rs*g0.w + c0.w);
                afr[ks][4] = f2bf((v[ks*8+4]-mu)*rs*g1.x + c1.x);
                afr[ks][5] = f2bf((v[ks*8+5]-mu)*rs*g1.y + c1.y);
                afr[ks][6] = f2bf((v[ks*8+6]-mu)*rs*g1.z + c1.z);
                afr[ks][7] = f2bf((v[ks*8+7]-mu)*rs*g1.w + c1.w);
            }
        }
        // ---- GEMM1 (K=128 -> 256) + GELU + GEMM2 (K=256 -> 64), K2-chunked.
        // chunk ks2 covers H cols ks2*32..+32 = GEMM1 outputs n1 = 2ks2, 2ks2+1.
        f32x4 acc2[4];
        #pragma unroll
        for (int n = 0; n < 4; ++n) acc2[n] = (f32x4){0.f, 0.f, 0.f, 0.f};
        for (int ks2 = 0; ks2 < 8; ++ks2) {
            f32x4 a1[2];
            a1[0] = (f32x4){0.f, 0.f, 0.f, 0.f};
            a1[1] = (f32x4){0.f, 0.f, 0.f, 0.f};
            #pragma unroll
            for (int ks1 = 0; ks1 < 4; ++ks1) {
                #pragma unroll
                for (int p = 0; p < 2; ++p) {
                    bf16x8 bf = *(const bf16x8*)(sW1 + (size_t)((((2*ks2+p) << 2) | ks1) * 64 + lane) * 8);
                    a1[p] = __builtin_amdgcn_mfma_f32_16x16x32_bf16(afr[ks1], bf, a1[p], 0, 0, 0);
                }
            }
            // bias+GELU -> chunk buffer [16 rows][32 cols] bf16, 64B rows, XOR (row&3)<<4
            #pragma unroll
            for (int p = 0; p < 2; ++p) {
                float bias = bd1[(2*ks2+p) * 16 + arow];
                #pragma unroll
                for (int rr = 0; rr < 4; ++rr) {
                    float vv = gelu(a1[p][rr] + bias);
                    int row = kgrp * 4 + rr;
                    int byte = row * 64 + (((p * 16 + arow) * 2) ^ ((row & 3) << 4));
                    myb[byte >> 1] = f2bf(vv);
                }
            }
            bf16x8 af2 = *(const bf16x8*)(myb + ((arow * 64 + ((kgrp * 16) ^ ((arow & 3) << 4))) >> 1));
            #pragma unroll
            for (int n2 = 0; n2 < 4; ++n2) {
                bf16x8 bf = *(const bf16x8*)(sW2 + (size_t)(((n2 << 3) | ks2) * 64 + lane) * 8);
                acc2[n2] = __builtin_amdgcn_mfma_f32_16x16x32_bf16(af2, bf, acc2[n2], 0, 0, 0);
            }
        }
        // ---- + bd2, LN_u over C=64 (row r2 = kgrp*4+rr spread over arow lanes)
        float hv[4][4];
        #pragma unroll
        for (int n2 = 0; n2 < 4; ++n2)
            #pragma unroll
            for (int rr = 0; rr < 4; ++rr)
                hv[n2][rr] = acc2[n2][rr] + bd2[n2 * 16 + arow];
        float mu_u[4], rs_u[4];
        #pragma unroll
        for (int rr = 0; rr < 4; ++rr) {
            float sr = hv[0][rr] + hv[1][rr] + hv[2][rr] + hv[3][rr];
            sr += __shfl_xor(sr, 1); sr += __shfl_xor(sr, 2);
            sr += __shfl_xor(sr, 4); sr += __shfl_xor(sr, 8);
            mu_u[rr] = sr * 0.015625f;
            float sq = 0.f;
            #pragma unroll
            for (int n2 = 0; n2 < 4; ++n2) { float d = hv[n2][rr] - mu_u[rr]; sq += d * d; }
            sq += __shfl_xor(sq, 1); sq += __shfl_xor(sq, 2);
            sq += __shfl_xor(sq, 4); sq += __shfl_xor(sq, 8);
            rs_u[rr] = rsqrtf(sq * 0.015625f + 1e-5f);
        }
        // normalized bf16 -> [16][64] buffer, 128B rows, XOR (row&7)<<4
        #pragma unroll
        for (int n2 = 0; n2 < 4; ++n2) {
            int c = n2 * 16 + arow;
            float gg = lnug[c], bb = lnub[c];
            #pragma unroll
            for (int rr = 0; rr < 4; ++rr) {
                float nv = (hv[n2][rr] - mu_u[rr]) * rs_u[rr] * gg + bb;
                int row = kgrp * 4 + rr;
                int byte = row * 128 + ((c * 2) ^ ((row & 7) << 4));
                myb[byte >> 1] = f2bf(nv);
            }
        }
        bf16x8 af3[2];
        #pragma unroll
        for (int ks3 = 0; ks3 < 2; ++ks3)
            af3[ks3] = *(const bf16x8*)(myb + ((arow * 128 + ((ks3 * 64 + kgrp * 16) ^ ((arow & 7) << 4))) >> 1));
        // ---- GEMM3 (K=64 -> 128) + GELU + GEMM4 (K=128 -> 128), in two halves
        f32x4 acc4[8];
        #pragma unroll
        for (int n = 0; n < 8; ++n) acc4[n] = (f32x4){0.f, 0.f, 0.f, 0.f};
        #pragma unroll
        for (int half = 0; half < 2; ++half) {
            f32x4 a3[4];
            #pragma unroll
            for (int n = 0; n < 4; ++n) a3[n] = (f32x4){0.f, 0.f, 0.f, 0.f};
            #pragma unroll
            for (int ks3 = 0; ks3 < 2; ++ks3) {
                #pragma unroll
                for (int n3h = 0; n3h < 4; ++n3h) {
                    int n3 = half * 4 + n3h;
                    bf16x8 bf = *(const bf16x8*)(sW3 + (size_t)(((n3 << 1) | ks3) * 64 + lane) * 8);
                    a3[n3h] = __builtin_amdgcn_mfma_f32_16x16x32_bf16(af3[ks3], bf, a3[n3h], 0, 0, 0);
                }
            }
            #pragma unroll
            for (int n3h = 0; n3h < 4; ++n3h) {
                float bias = bu1[(half * 4 + n3h) * 16 + arow];
                #pragma unroll
                for (int rr = 0; rr < 4; ++rr) {
                    float vv = gelu(a3[n3h][rr] + bias);
                    int row = kgrp * 4 + rr;
                    int byte = row * 128 + (((n3h * 16 + arow) * 2) ^ ((row & 7) << 4));
                    myb[byte >> 1] = f2bf(vv);
                }
            }
            #pragma unroll
            for (int k4 = 0; k4 < 2; ++k4) {
                bf16x8 afu = *(const bf16x8*)(myb + ((arow * 128 + ((k4 * 64 + kgrp * 16) ^ ((arow & 7) << 4))) >> 1));
                #pragma unroll
                for (int n4 = 0; n4 < 8; ++n4) {
                    bf16x8 bf = *(const bf16x8*)(sW4 + (size_t)(((n4 << 2) | (half * 2 + k4)) * 64 + lane) * 8);
                    acc4[n4] = __builtin_amdgcn_mfma_f32_16x16x32_bf16(afu, bf, acc4[n4], 0, 0, 0);
                }
            }
        }
        // ---- epilogue: + bu2, broadcast row to every subnode position
        #pragma unroll
        for (int rr = 0; rr < 4; ++rr) {
            int gi2 = row0 + kgrp * 4 + rr;
            if (gi2 >= nrows) continue;
            int nd = list[gi2];
            int c2 = pernode[nd * 8 + g];
            int o2 = cursor[nd * 8 + g] - c2;
            float vals[8];
            #pragma unroll
            for (int n4 = 0; n4 < 8; ++n4) vals[n4] = acc4[n4][rr] + bu2[n4 * 16 + arow];
            for (int j = 0; j < c2; ++j) {
                int s = pos_g[o2 + j];
                float* op = out_g + (size_t)s * DD + arow;
                #pragma unroll
                for (int n4 = 0; n4 < 8; ++n4) op[n4 * 16] = vals[n4];
            }
        }
    }
}

extern "C" void kernel_launch(void* const* d_in, const int* in_sizes, int n_in,
                              void* d_out, int out_size, void* d_ws, size_t ws_size,
                              hipStream_t stream) {
    const float* x       = (const float*)d_in[0];
    const int*   indices = (const int*)d_in[1];
    const float* bd      = (const float*)d_in[2];
    const float* ln_d_g  = (const float*)d_in[3];
    const float* ln_d_b  = (const float*)d_in[4];
    const float* Wd1     = (const float*)d_in[5];
    const float* bd1     = (const float*)d_in[6];
    const float* Wd2     = (const float*)d_in[7];
    const float* bd2     = (const float*)d_in[8];
    const float* ln_u_g  = (const float*)d_in[9];
    const float* ln_u_b  = (const float*)d_in[10];
    const float* Wu1     = (const float*)d_in[11];
    const float* bu1     = (const float*)d_in[12];
    const float* Wu2     = (const float*)d_in[13];
    const float* bu2     = (const float*)d_in[14];
    float* out = (float*)d_out;

    char* ws = (char*)d_ws;
    size_t o = 0;
    auto alloc_b = [&](size_t bytes) { char* p = ws + o; o = (o + bytes + 255) & ~(size_t)255; return p; };
    int*   pernode  = (int*)alloc_b((size_t)NN * 8 * 4);
    int*   cursor   = (int*)alloc_b((size_t)NN * 8 * 4);
    int*   lists    = (int*)alloc_b((size_t)8 * NS * 4);
    int*   positions= (int*)alloc_b((size_t)8 * NS * 4);
    int*   cnts     = (int*)alloc_b(8 * 4);
    int*   allocg   = (int*)alloc_b(8 * 4);
    short* pW1      = (short*)alloc_b((size_t)4096 * 16);
    short* pW2      = (short*)alloc_b((size_t)2048 * 16);
    short* pW3      = (short*)alloc_b((size_t)1024 * 16);
    short* pW4      = (short*)alloc_b((size_t)2048 * 16);

    hipMemsetAsync(pernode, 0, (size_t)NN * 8 * 4, stream);
    hipMemsetAsync(cnts, 0, 8 * 4, stream);
    hipMemsetAsync(allocg, 0, 8 * 4, stream);

    prep_weights<<<16, 256, 0, stream>>>(Wd1, pW1, 4, 4096, 256);
    prep_weights<<<8, 256, 0, stream>>>(Wd2, pW2, 8, 2048, 64);
    prep_weights<<<4, 256, 0, stream>>>(Wu1, pW3, 2, 1024, 128);
    prep_weights<<<8, 256, 0, stream>>>(Wu2, pW4, 4, 2048, 128);

    flag_kernel<<<(G8 * NS + 255) / 256, 256, 0, stream>>>(indices, pernode);
    compact_kernel<<<dim3((NN + 255) / 256, G8), 256, 0, stream>>>(pernode, cursor,
                                                                   lists, cnts, allocg);
    fill_kernel<<<(G8 * NS + 255) / 256, 256, 0, stream>>>(indices, cursor, positions);
    fused_kernel<<<256, 512, 0, stream>>>(x, bd, ln_d_g, ln_d_b, pW1, pW2, pW3, pW4,
                                          bd1, bd2, ln_u_g, ln_u_b, bu1, bu2,
                                          lists, cnts, pernode, cursor, positions, out);
}